// Round 10
// baseline (35.434 us; speedup 1.0000x reference)
//
#include <hip/hip_runtime.h>

#ifndef __has_builtin
#define __has_builtin(x) 0
#endif

__device__ __forceinline__ float fexp2(float x) {
#if __has_builtin(__builtin_amdgcn_exp2f)
    return __builtin_amdgcn_exp2f(x);
#else
    return exp2f(x);
#endif
}
__device__ __forceinline__ float frcp(float x) {
#if __has_builtin(__builtin_amdgcn_rcpf)
    return __builtin_amdgcn_rcpf(x);
#else
    return 1.0f / x;
#endif
}

constexpr int TT = 32;    // directions T
constexpr int SS = 32;    // steps S
constexpr int BB = 64;    // graphs B
constexpr int CPB_N = 8;  // chunks per graph, node part  -> 512 node blocks
constexpr int CPB_E = 16; // edge chunks                  -> 1024 edge blocks
constexpr int ZB = 16;    // out-zeroing blocks
constexpr int GEB = 128;  // ge8 precompute blocks
constexpr int QCAP = 2048; // LDS edge queue; == subround size => overflow impossible
constexpr float FL = 50.0f * 1.44269504088896340736f;  // steepness * log2(e)
constexpr float QS = 65536.0f;                          // fixed-point scale 2^16
constexpr float IQS = 1.0f / 65536.0f;

// ---- K1: bounds over sorted batch + out-zero + ge8[e] = graph of edge e ----
__global__ __launch_bounds__(256) void prep_k(
    const int* __restrict__ batch, const int* __restrict__ src,
    int N, int E, int nB,
    int* __restrict__ starts, unsigned char* __restrict__ ge8,
    float* __restrict__ out)
{
    if ((int)blockIdx.x < nB) {
        const int n = blockIdx.x * 256 + threadIdx.x;
        if (n >= N) return;
        const int g = batch[n];
        const int gp = (n == 0) ? -1 : batch[n - 1];
        for (int g2 = gp + 1; g2 <= g; ++g2) starts[g2] = n;
        if (n == N - 1)
            for (int g2 = g + 1; g2 <= BB; ++g2) starts[g2] = N;
    } else if ((int)blockIdx.x < nB + ZB) {
        float4* o4 = (float4*)out;
        for (int i = (blockIdx.x - nB) * 256 + threadIdx.x; i < BB * SS * TT / 4;
             i += ZB * 256)
            o4[i] = float4{0.f, 0.f, 0.f, 0.f};
    } else {
        const int b = blockIdx.x - nB - ZB;
        for (int e = b * 256 + threadIdx.x; e < E; e += GEB * 256)
            ge8[e] = (unsigned char)batch[src[e]];
    }
}

// ---- K2: node-ECT blocks (0..511) ∥ edge scan-compact-ECT blocks (512..1535) ----
// Window-3 sigmoid + histogram-suffix, u32 fixed-point LDS atomics (round-6 core).
__global__ __launch_bounds__(256) void ect_k(
    const float* __restrict__ x, const float* __restrict__ v,
    const float* __restrict__ lin,
    const int* __restrict__ src, const int* __restrict__ dst,
    const unsigned char* __restrict__ ge8,
    const int* __restrict__ starts, int E, float* __restrict__ out)
{
    __shared__ unsigned accS[TT][SS + 1];
    __shared__ unsigned cntS[TT][SS + 1];
    __shared__ unsigned part[TT][9];
    __shared__ int q[QCAP];
    __shared__ int qcnt;
    for (int i = threadIdx.x; i < TT * (SS + 1); i += 256) {
        ((unsigned*)accS)[i] = 0u;
        ((unsigned*)cntS)[i] = 0u;
    }
    const int t = threadIdx.x & 31;
    const int pr = threadIdx.x >> 5;
    const float v0 = v[t], v1 = v[TT + t], v2 = v[2 * TT + t];
    const float l0 = lin[0];
    const float dS = lin[1] - l0;
    const float invD = frcp(dS);
    const float fld = FL * dS;                 // ~5.12 exp2-units per bin
    const float pm1 = fexp2(fld), pp1 = fexp2(-fld);
    __syncthreads();

    auto accum = [&](float h) {
        const float hl0 = h - l0;
        float fj = rintf(hl0 * invD);
        fj = fminf(34.f, fmaxf(-2.f, fj));
        const int j = (int)fj;
        const float delta = fmaf(-fj, dS, hl0);   // h - l_j
        const float ucen = fexp2(FL * delta);     // in [0.17, 5.9] when unclamped
        const unsigned q0 = __float2uint_rn(QS * frcp(fmaf(ucen, pm1, 1.f))); // s=j-1
        const unsigned q1 = __float2uint_rn(QS * frcp(1.f + ucen));           // s=j
        const unsigned q2 = __float2uint_rn(QS * frcp(fmaf(ucen, pp1, 1.f))); // s=j+1
        if (j + 2 < SS) atomicAdd(&cntS[t][j + 2], 1u);
        if (1 <= j && j <= SS) atomicAdd(&accS[t][j - 1], q0);
        if (0 <= j && j < SS)  atomicAdd(&accS[t][j], q1);
        if (-1 <= j && j < SS - 1) atomicAdd(&accS[t][j + 1], q2);
    };

    const bool edge = blockIdx.x >= BB * CPB_N;
    int g;
    if (!edge) {
        const int bid = blockIdx.x;
        g = bid / CPB_N;
        const int c = bid % CPB_N;
        const int s0 = starts[g], s1 = starts[g + 1];
        const int chunk = (s1 - s0 + CPB_N - 1) / CPB_N;
        const int lo = s0 + c * chunk, hi = min(s1, lo + chunk);
        for (int p = lo + pr; p < hi; p += 8)
            accum(fmaf(x[3 * p], v0, fmaf(x[3 * p + 1], v1, x[3 * p + 2] * v2)));
    } else {
        const int bid = blockIdx.x - BB * CPB_N;
        g = bid / CPB_E;
        const int c = bid % CPB_E;
        const int chunk = (E + CPB_E - 1) / CPB_E;
        const int lo = c * chunk, hi = min(E, lo + chunk);
        const unsigned char gg = (unsigned char)g;
        for (int sub = lo; sub < hi; sub += QCAP) {
            const int send = min(hi, sub + QCAP);
            __syncthreads();                     // prior process phase done reading q
            if (threadIdx.x == 0) qcnt = 0;
            __syncthreads();
            for (int e = sub + (int)threadIdx.x; e < send; e += 256)
                if (ge8[e] == gg) { const int pos = atomicAdd(&qcnt, 1); q[pos] = e; }
            __syncthreads();
            const int nq = qcnt;
            for (int i = pr; i < nq; i += 8) {
                const int e = q[i];
                const int sn = src[e], dn = dst[e];
                const float hs = fmaf(x[3 * sn], v0, fmaf(x[3 * sn + 1], v1, x[3 * sn + 2] * v2));
                const float hd = fmaf(x[3 * dn], v0, fmaf(x[3 * dn + 1], v1, x[3 * dn + 2] * v2));
                accum(fmaxf(hs, hd));
            }
        }
    }
    __syncthreads();
    // two-level scan: thread (t, q=pr) owns s in [4q, 4q+4)
    const unsigned c0 = cntS[t][4 * pr], c1 = cntS[t][4 * pr + 1];
    const unsigned c2 = cntS[t][4 * pr + 2], c3 = cntS[t][4 * pr + 3];
    part[t][pr + 1] = c0 + c1 + c2 + c3;
    if (pr == 0) part[t][0] = 0u;
    __syncthreads();
    if (pr == 0) {
        unsigned r = 0u;
#pragma unroll
        for (int qq = 1; qq <= 8; ++qq) { r += part[t][qq]; part[t][qq] = r; }
    }
    __syncthreads();
    unsigned run = part[t][pr];
    const float sign = edge ? -1.f : 1.f;
    float* o = out + (size_t)g * SS * TT;
    run += c0;
    atomicAdd(&o[(4 * pr + 0) * TT + t], sign * fmaf((float)accS[t][4 * pr + 0], IQS, (float)run));
    run += c1;
    atomicAdd(&o[(4 * pr + 1) * TT + t], sign * fmaf((float)accS[t][4 * pr + 1], IQS, (float)run));
    run += c2;
    atomicAdd(&o[(4 * pr + 2) * TT + t], sign * fmaf((float)accS[t][4 * pr + 2], IQS, (float)run));
    run += c3;
    atomicAdd(&o[(4 * pr + 3) * TT + t], sign * fmaf((float)accS[t][4 * pr + 3], IQS, (float)run));
}

extern "C" void kernel_launch(void* const* d_in, const int* in_sizes, int n_in,
                              void* d_out, int out_size, void* d_ws, size_t ws_size,
                              hipStream_t stream) {
    const float* x   = (const float*)d_in[0];
    const float* v   = (const float*)d_in[1];
    const float* lin = (const float*)d_in[2];
    const int* edge_index = (const int*)d_in[3];
    const int* batch = (const int*)d_in[4];

    const int N = in_sizes[0] / 3;
    const int E = in_sizes[3] / 2;
    const int* src = edge_index;       // edge_index[0][:]
    const int* dst = edge_index + E;   // edge_index[1][:]
    float* out = (float*)d_out;

    char* ws = (char*)d_ws;
    int* starts        = (int*)ws;           // 65 ints
    unsigned char* ge8 = (unsigned char*)(ws + 512);  // E bytes

    const int nB = (N + 255) / 256;
    prep_k<<<nB + ZB + GEB, 256, 0, stream>>>(batch, src, N, E, nB, starts, ge8, out);
    ect_k<<<BB * (CPB_N + CPB_E), 256, 0, stream>>>(x, v, lin, src, dst, ge8,
                                                    starts, E, out);
}